// Round 1
// baseline (916.588 us; speedup 1.0000x reference)
//
#include <hip/hip_runtime.h>
#include <math.h>

// Problem constants (AttentionBlock: B=4, C=512, T=2048, H=8, dh=64, G=32)
#define Bb 4
#define Cc 512
#define Tt 2048
#define Hh 8
#define Gg 32

// ---------------------------------------------------------------------------
// Kernel 1: GroupNorm.  One block per (b, group). Group = 16 channels x 2048 t
// = one contiguous 32768-float span of x. Two passes (sum/sumsq, normalize).
// ---------------------------------------------------------------------------
__global__ __launch_bounds__(256) void gn_kernel(const float* __restrict__ x,
                                                 const float* __restrict__ gamma,
                                                 const float* __restrict__ beta,
                                                 float* __restrict__ h) {
  const int blk = blockIdx.x;
  const int b = blk >> 5, g = blk & 31;
  const size_t base = ((size_t)b * Cc + (size_t)g * 16) * Tt;
  const int N = 16 * Tt;  // 32768
  const int tid = threadIdx.x;

  float s = 0.f, ss = 0.f;
  for (int i = tid * 4; i < N; i += 1024) {
    const float4 v = *(const float4*)(x + base + i);
    s  += v.x + v.y + v.z + v.w;
    ss += v.x * v.x + v.y * v.y + v.z * v.z + v.w * v.w;
  }
#pragma unroll
  for (int off = 32; off >= 1; off >>= 1) {
    s  += __shfl_down(s, off);
    ss += __shfl_down(ss, off);
  }
  __shared__ float rs[4], rss[4], stats[2];
  const int wid = tid >> 6;
  if ((tid & 63) == 0) { rs[wid] = s; rss[wid] = ss; }
  __syncthreads();
  if (tid == 0) {
    const float a = rs[0] + rs[1] + rs[2] + rs[3];
    const float c = rss[0] + rss[1] + rss[2] + rss[3];
    const float mean = a / (float)N;
    const float var = c / (float)N - mean * mean;
    stats[0] = mean;
    stats[1] = rsqrtf(var + 1e-5f);
  }
  __syncthreads();
  const float mean = stats[0], rstd = stats[1];
  for (int i = tid * 4; i < N; i += 1024) {
    const float4 v = *(const float4*)(x + base + i);
    const int c = g * 16 + (i >> 11);  // i / 2048
    const float ga = gamma[c] * rstd, be = beta[c];
    float4 o;
    o.x = (v.x - mean) * ga + be;
    o.y = (v.y - mean) * ga + be;
    o.z = (v.z - mean) * ga + be;
    o.w = (v.w - mean) * ga + be;
    *(float4*)(h + base + i) = o;
  }
}

// ---------------------------------------------------------------------------
// Kernel 2/4: fp32 GEMM  out[b][m][n] = sum_k W[m][k] * X[b][k][n] + bias[m]
//             (+ optional residual). Tile 64x64, BK=32, 256 thr, 4x4/thread.
// LDS pads: Wl rows 36 words (scalar/vec reads 2-way max), Xl rows 68 words.
// ---------------------------------------------------------------------------
__global__ __launch_bounds__(256) void gemm_kernel(const float* __restrict__ W,
                                                   const float* __restrict__ X,
                                                   const float* __restrict__ bias,
                                                   const float* __restrict__ res,
                                                   float* __restrict__ out,
                                                   int M, int K, int N) {
  __shared__ __align__(16) float Wl[64][36];
  __shared__ __align__(16) float Xl[32][68];

  const int tid = threadIdx.x;
  const int tx = tid & 15, ty = tid >> 4;
  const int tx4 = tx * 4, ty4 = ty * 4;
  const int m0 = blockIdx.y * 64, n0 = blockIdx.x * 64;
  const size_t bz = blockIdx.z;
  X += bz * (size_t)K * N;
  out += bz * (size_t)M * N;
  if (res) res += bz * (size_t)M * N;

  float acc[4][4] = {};

  const int r0 = tid >> 3;            // 0..31 (W tile row)
  const int c4w = (tid & 7) * 4;      // 0..28 (W tile k-col, float4)
  const int kx = tid >> 4;            // 0..15 (X tile k-row)
  const int f4x = (tid & 15) * 4;     // 0..60 (X tile n-col, float4)

  for (int k0 = 0; k0 < K; k0 += 32) {
    *(float4*)&Wl[r0][c4w]      = *(const float4*)(W + (size_t)(m0 + r0) * K + k0 + c4w);
    *(float4*)&Wl[r0 + 32][c4w] = *(const float4*)(W + (size_t)(m0 + r0 + 32) * K + k0 + c4w);
    *(float4*)&Xl[kx][f4x]      = *(const float4*)(X + (size_t)(k0 + kx) * N + n0 + f4x);
    *(float4*)&Xl[kx + 16][f4x] = *(const float4*)(X + (size_t)(k0 + kx + 16) * N + n0 + f4x);
    __syncthreads();

#pragma unroll
    for (int k4 = 0; k4 < 32; k4 += 4) {
      const float4 a0 = *(const float4*)&Wl[ty4 + 0][k4];
      const float4 a1 = *(const float4*)&Wl[ty4 + 1][k4];
      const float4 a2 = *(const float4*)&Wl[ty4 + 2][k4];
      const float4 a3 = *(const float4*)&Wl[ty4 + 3][k4];
#pragma unroll
      for (int kk = 0; kk < 4; ++kk) {
        const float4 xv = *(const float4*)&Xl[k4 + kk][tx4];
        const float w0 = ((const float*)&a0)[kk];
        const float w1 = ((const float*)&a1)[kk];
        const float w2 = ((const float*)&a2)[kk];
        const float w3 = ((const float*)&a3)[kk];
        acc[0][0] = fmaf(w0, xv.x, acc[0][0]);
        acc[0][1] = fmaf(w0, xv.y, acc[0][1]);
        acc[0][2] = fmaf(w0, xv.z, acc[0][2]);
        acc[0][3] = fmaf(w0, xv.w, acc[0][3]);
        acc[1][0] = fmaf(w1, xv.x, acc[1][0]);
        acc[1][1] = fmaf(w1, xv.y, acc[1][1]);
        acc[1][2] = fmaf(w1, xv.z, acc[1][2]);
        acc[1][3] = fmaf(w1, xv.w, acc[1][3]);
        acc[2][0] = fmaf(w2, xv.x, acc[2][0]);
        acc[2][1] = fmaf(w2, xv.y, acc[2][1]);
        acc[2][2] = fmaf(w2, xv.z, acc[2][2]);
        acc[2][3] = fmaf(w2, xv.w, acc[2][3]);
        acc[3][0] = fmaf(w3, xv.x, acc[3][0]);
        acc[3][1] = fmaf(w3, xv.y, acc[3][1]);
        acc[3][2] = fmaf(w3, xv.z, acc[3][2]);
        acc[3][3] = fmaf(w3, xv.w, acc[3][3]);
      }
    }
    __syncthreads();
  }

#pragma unroll
  for (int i = 0; i < 4; ++i) {
    const int m = m0 + ty4 + i;
    const float bv = bias[m];
    float4 o;
    o.x = acc[i][0] + bv;
    o.y = acc[i][1] + bv;
    o.z = acc[i][2] + bv;
    o.w = acc[i][3] + bv;
    if (res) {
      const float4 r = *(const float4*)(res + (size_t)m * N + n0 + tx4);
      o.x += r.x; o.y += r.y; o.z += r.z; o.w += r.w;
    }
    *(float4*)(out + (size_t)m * N + n0 + tx4) = o;
  }
}

// ---------------------------------------------------------------------------
// Kernel 3: flash attention (fp32). One block per (b, h, 64-query tile).
// qkv layout: row (b*1536 + h*192 + {0,64,128} + c), col t.  Scale^2 = 1/8
// folded into Q at load. Online softmax, 16-lane shfl row reductions.
// Output written to attno[b][h*64+c][t] (staged via LDS for coalescing).
// ---------------------------------------------------------------------------
__global__ __launch_bounds__(256) void attn_kernel(const float* __restrict__ qkv,
                                                   float* __restrict__ attno) {
  __shared__ __align__(16) float Ql[64][68];  // [c][q]
  __shared__ __align__(16) float Kl[64][68];  // [c][s]
  __shared__ __align__(16) float Pl[64][68];  // [q][s]; reused as O[c][q] at end
  __shared__ float Vl[64][65];                // [c][s], odd pitch for 2-way reads
  __shared__ float mrow[64], lrow[64];

  const int tid = threadIdx.x;
  const int tx = tid & 15, ty = tid >> 4;
  const int tx4 = tx * 4, ty4 = ty * 4;
  const int bh = blockIdx.y;
  const int b = bh >> 3, hd = bh & 7;
  const int q0 = blockIdx.x * 64;
  const float* qb = qkv + ((size_t)b * (3 * Cc) + (size_t)hd * 192) * Tt;

  const int cr = tid >> 4;        // 0..15 tile row loader
  const int f4 = (tid & 15) * 4;  // 0..60 float4 col

  // Load Q tile (pre-scaled by 1/sqrt(dh) = 1/8)
#pragma unroll
  for (int c0 = 0; c0 < 64; c0 += 16) {
    float4 v = *(const float4*)(qb + (size_t)(c0 + cr) * Tt + q0 + f4);
    v.x *= 0.125f; v.y *= 0.125f; v.z *= 0.125f; v.w *= 0.125f;
    *(float4*)&Ql[c0 + cr][f4] = v;
  }
  if (tid < 64) { mrow[tid] = -1e30f; lrow[tid] = 0.f; }
  float acc[4][4] = {};  // O[q = ty4+i][c = tx4+j]
  __syncthreads();

  for (int s0 = 0; s0 < Tt; s0 += 64) {
    // Load K and V tiles
#pragma unroll
    for (int c0 = 0; c0 < 64; c0 += 16) {
      *(float4*)&Kl[c0 + cr][f4] =
          *(const float4*)(qb + (size_t)(64 + c0 + cr) * Tt + s0 + f4);
      const float4 v = *(const float4*)(qb + (size_t)(128 + c0 + cr) * Tt + s0 + f4);
      Vl[c0 + cr][f4 + 0] = v.x;
      Vl[c0 + cr][f4 + 1] = v.y;
      Vl[c0 + cr][f4 + 2] = v.z;
      Vl[c0 + cr][f4 + 3] = v.w;
    }
    __syncthreads();

    // S = Q^T K  (inner dim = channel)
    float sc[4][4] = {};
#pragma unroll 8
    for (int c = 0; c < 64; ++c) {
      const float4 qv = *(const float4*)&Ql[c][ty4];
      const float4 kv = *(const float4*)&Kl[c][tx4];
      sc[0][0] = fmaf(qv.x, kv.x, sc[0][0]);
      sc[0][1] = fmaf(qv.x, kv.y, sc[0][1]);
      sc[0][2] = fmaf(qv.x, kv.z, sc[0][2]);
      sc[0][3] = fmaf(qv.x, kv.w, sc[0][3]);
      sc[1][0] = fmaf(qv.y, kv.x, sc[1][0]);
      sc[1][1] = fmaf(qv.y, kv.y, sc[1][1]);
      sc[1][2] = fmaf(qv.y, kv.z, sc[1][2]);
      sc[1][3] = fmaf(qv.y, kv.w, sc[1][3]);
      sc[2][0] = fmaf(qv.z, kv.x, sc[2][0]);
      sc[2][1] = fmaf(qv.z, kv.y, sc[2][1]);
      sc[2][2] = fmaf(qv.z, kv.z, sc[2][2]);
      sc[2][3] = fmaf(qv.z, kv.w, sc[2][3]);
      sc[3][0] = fmaf(qv.w, kv.x, sc[3][0]);
      sc[3][1] = fmaf(qv.w, kv.y, sc[3][1]);
      sc[3][2] = fmaf(qv.w, kv.z, sc[3][2]);
      sc[3][3] = fmaf(qv.w, kv.w, sc[3][3]);
    }

    // Online softmax per q-row (row spread over 16 tx lanes, same wave)
    float alpha_[4];
#pragma unroll
    for (int i = 0; i < 4; ++i) {
      const int q = ty4 + i;
      float mx = fmaxf(fmaxf(sc[i][0], sc[i][1]), fmaxf(sc[i][2], sc[i][3]));
#pragma unroll
      for (int off = 1; off < 16; off <<= 1) mx = fmaxf(mx, __shfl_xor(mx, off));
      const float mold = mrow[q];
      const float mnew = fmaxf(mold, mx);
      float rsum = 0.f;
#pragma unroll
      for (int j = 0; j < 4; ++j) {
        const float p = __expf(sc[i][j] - mnew);
        sc[i][j] = p;
        rsum += p;
      }
#pragma unroll
      for (int off = 1; off < 16; off <<= 1) rsum += __shfl_xor(rsum, off);
      const float al = __expf(mold - mnew);
      alpha_[i] = al;
      if (tx == 0) {
        mrow[q] = mnew;
        lrow[q] = lrow[q] * al + rsum;
      }
      *(float4*)&Pl[q][tx4] = make_float4(sc[i][0], sc[i][1], sc[i][2], sc[i][3]);
    }
#pragma unroll
    for (int i = 0; i < 4; ++i) {
      acc[i][0] *= alpha_[i];
      acc[i][1] *= alpha_[i];
      acc[i][2] *= alpha_[i];
      acc[i][3] *= alpha_[i];
    }
    __syncthreads();

    // O += P V   (inner dim = s)
#pragma unroll 8
    for (int s = 0; s < 64; ++s) {
      const float p0 = Pl[ty4 + 0][s];
      const float p1 = Pl[ty4 + 1][s];
      const float p2 = Pl[ty4 + 2][s];
      const float p3 = Pl[ty4 + 3][s];
      const float v0 = Vl[tx4 + 0][s];
      const float v1 = Vl[tx4 + 1][s];
      const float v2 = Vl[tx4 + 2][s];
      const float v3 = Vl[tx4 + 3][s];
      acc[0][0] = fmaf(p0, v0, acc[0][0]);
      acc[0][1] = fmaf(p0, v1, acc[0][1]);
      acc[0][2] = fmaf(p0, v2, acc[0][2]);
      acc[0][3] = fmaf(p0, v3, acc[0][3]);
      acc[1][0] = fmaf(p1, v0, acc[1][0]);
      acc[1][1] = fmaf(p1, v1, acc[1][1]);
      acc[1][2] = fmaf(p1, v2, acc[1][2]);
      acc[1][3] = fmaf(p1, v3, acc[1][3]);
      acc[2][0] = fmaf(p2, v0, acc[2][0]);
      acc[2][1] = fmaf(p2, v1, acc[2][1]);
      acc[2][2] = fmaf(p2, v2, acc[2][2]);
      acc[2][3] = fmaf(p2, v3, acc[2][3]);
      acc[3][0] = fmaf(p3, v0, acc[3][0]);
      acc[3][1] = fmaf(p3, v1, acc[3][1]);
      acc[3][2] = fmaf(p3, v2, acc[3][2]);
      acc[3][3] = fmaf(p3, v3, acc[3][3]);
    }
    __syncthreads();
  }

  // Epilogue: divide by l, stage O as [c][q] in Pl, write coalesced rows.
  float invl[4];
#pragma unroll
  for (int i = 0; i < 4; ++i) invl[i] = 1.f / lrow[ty4 + i];
#pragma unroll
  for (int i = 0; i < 4; ++i) {
#pragma unroll
    for (int j = 0; j < 4; ++j) Pl[tx4 + j][ty4 + i] = acc[i][j] * invl[i];
  }
  __syncthreads();
  for (int it = tid; it < 1024; it += 256) {
    const int c = it >> 4, f = (it & 15) * 4;
    const float4 v = *(const float4*)&Pl[c][f];
    *(float4*)(attno + ((size_t)b * Cc + (size_t)hd * 64 + c) * Tt + q0 + f) = v;
  }
}

// ---------------------------------------------------------------------------
extern "C" void kernel_launch(void* const* d_in, const int* in_sizes, int n_in,
                              void* d_out, int out_size, void* d_ws, size_t ws_size,
                              hipStream_t stream) {
  const float* x      = (const float*)d_in[0];
  const float* gamma  = (const float*)d_in[1];
  const float* beta   = (const float*)d_in[2];
  const float* w_qkv  = (const float*)d_in[3];
  const float* b_qkv  = (const float*)d_in[4];
  const float* w_proj = (const float*)d_in[5];
  const float* b_proj = (const float*)d_in[6];
  float* out = (float*)d_out;

  // Workspace: h (4M f), qkv (12M f), attno (4M f)  => 80 MB total
  float* h     = (float*)d_ws;
  float* qkv   = h + (size_t)Bb * Cc * Tt;
  float* attno = qkv + (size_t)Bb * 3 * Cc * Tt;

  gn_kernel<<<dim3(Bb * Gg), 256, 0, stream>>>(x, gamma, beta, h);
  gemm_kernel<<<dim3(Tt / 64, (3 * Cc) / 64, Bb), 256, 0, stream>>>(
      w_qkv, h, b_qkv, nullptr, qkv, 3 * Cc, Cc, Tt);
  attn_kernel<<<dim3(Tt / 64, Bb * Hh), 256, 0, stream>>>(qkv, attno);
  gemm_kernel<<<dim3(Tt / 64, Cc / 64, Bb), 256, 0, stream>>>(
      w_proj, attno, b_proj, x, out, Cc, Cc, Tt);
}

// Round 2
// 166.494 us; speedup vs baseline: 5.5052x; 5.5052x over previous
//
#include <hip/hip_runtime.h>
#include <math.h>
#include <stdint.h>

// Problem constants: B=4, C=512, T=2048, H=8, dh=64, G=32
#define Bb 4
#define Cc 512
#define Tt 2048
#define Hh 8

typedef __attribute__((ext_vector_type(8))) short short8;   // 8 bf16 (4 VGPR) MFMA operand
typedef __attribute__((ext_vector_type(4))) float f32x4;    // MFMA accumulator
typedef __attribute__((ext_vector_type(8))) unsigned short u16x8;

__device__ __forceinline__ unsigned short f2bf(float f) {   // fp32 -> bf16 RNE
  union { float f; uint32_t u; } v; v.f = f;
  uint32_t r = v.u + 0x7FFFu + ((v.u >> 16) & 1u);
  return (unsigned short)(r >> 16);
}

__device__ __forceinline__ void async16(const void* g, void* l) {
  __builtin_amdgcn_global_load_lds(
      (const __attribute__((address_space(1))) uint32_t*)g,
      (__attribute__((address_space(3))) uint32_t*)l, 16, 0, 0);
}

// ---------------------------------------------------------------------------
// K1: per-(b,group) mean/rstd.  Block = b*32+g over contiguous 32768 floats.
// ---------------------------------------------------------------------------
__global__ __launch_bounds__(256) void gn_stats(const float* __restrict__ x,
                                                float* __restrict__ stats) {
  const int blk = blockIdx.x;
  const size_t base = (size_t)blk * 16 * Tt;
  const int N = 16 * Tt;
  const int tid = threadIdx.x;
  float s = 0.f, ss = 0.f;
  for (int i = tid * 4; i < N; i += 1024) {
    const float4 v = *(const float4*)(x + base + i);
    s += v.x + v.y + v.z + v.w;
    ss += v.x * v.x + v.y * v.y + v.z * v.z + v.w * v.w;
  }
#pragma unroll
  for (int off = 32; off >= 1; off >>= 1) {
    s += __shfl_down(s, off);
    ss += __shfl_down(ss, off);
  }
  __shared__ float rs[4], rss[4];
  const int wid = tid >> 6;
  if ((tid & 63) == 0) { rs[wid] = s; rss[wid] = ss; }
  __syncthreads();
  if (tid == 0) {
    const float a = rs[0] + rs[1] + rs[2] + rs[3];
    const float c = rss[0] + rss[1] + rss[2] + rss[3];
    const float mean = a / (float)N;
    const float var = c / (float)N - mean * mean;
    stats[blk * 2] = mean;
    stats[blk * 2 + 1] = rsqrtf(var + 1e-5f);
  }
}

// ---------------------------------------------------------------------------
// K2: normalize + convert + transpose: x fp32 [b][c][t] -> hT bf16 [b][t][c].
// 64x64 tiles via LDS.
// ---------------------------------------------------------------------------
__global__ __launch_bounds__(256) void norm_trans(const float* __restrict__ x,
                                                  const float* __restrict__ stats,
                                                  const float* __restrict__ gamma,
                                                  const float* __restrict__ beta,
                                                  unsigned short* __restrict__ hT) {
  __shared__ unsigned short Tl[64][72];
  const int tid = threadIdx.x;
  const int b = blockIdx.z, c0 = blockIdx.y * 64, t0 = blockIdx.x * 64;
  const int cl = tid >> 2, j16 = (tid & 3) * 16;
  const int c = c0 + cl;
  const int grp = c >> 4;
  const float mean = stats[((size_t)b * 32 + grp) * 2];
  const float rstd = stats[((size_t)b * 32 + grp) * 2 + 1];
  const float ga = gamma[c] * rstd;
  const float be = beta[c] - mean * ga;
  const float* src = x + ((size_t)b * Cc + c) * Tt + t0 + j16;
#pragma unroll
  for (int q = 0; q < 4; ++q) {
    const float4 v = *(const float4*)(src + q * 4);
    Tl[j16 + q * 4 + 0][cl] = f2bf(v.x * ga + be);
    Tl[j16 + q * 4 + 1][cl] = f2bf(v.y * ga + be);
    Tl[j16 + q * 4 + 2][cl] = f2bf(v.z * ga + be);
    Tl[j16 + q * 4 + 3][cl] = f2bf(v.w * ga + be);
  }
  __syncthreads();
  const int tl = tid >> 2, i16 = (tid & 3) * 16;
  unsigned short* dst = hT + ((size_t)b * Tt + t0 + tl) * Cc + c0 + i16;
  *(u16x8*)dst = *(const u16x8*)&Tl[tl][i16];
  *(u16x8*)(dst + 8) = *(const u16x8*)&Tl[tl][i16 + 8];
}

// ---------------------------------------------------------------------------
// K3: fp32 -> bf16 convert (weights).
// ---------------------------------------------------------------------------
__global__ __launch_bounds__(256) void cvt_bf16(const float* __restrict__ in,
                                                unsigned short* __restrict__ out, int n4) {
  const int i = blockIdx.x * 256 + threadIdx.x;
  if (i < n4) {
    const float4 v = *(const float4*)(in + (size_t)i * 4);
    ushort4 o;
    o.x = f2bf(v.x); o.y = f2bf(v.y); o.z = f2bf(v.z); o.w = f2bf(v.w);
    *(ushort4*)(out + (size_t)i * 4) = o;
  }
}

// ---------------------------------------------------------------------------
// K4: bf16 transpose 64x64: qkv [b][3C][t] (Q,K parts) -> qkt [(bh*2+w)][t][64]
// ---------------------------------------------------------------------------
__global__ __launch_bounds__(256) void qk_trans(const unsigned short* __restrict__ qkv,
                                                unsigned short* __restrict__ qkt) {
  __shared__ unsigned short Tl[64][72];
  const int tid = threadIdx.x;
  const int t0 = blockIdx.x * 64;
  const int bhw = blockIdx.y;  // (b*8+h)*2 + which
  const int b = bhw >> 4, hw = bhw & 15;
  const int h = hw >> 1, which = hw & 1;
  const unsigned short* src =
      qkv + ((size_t)b * (3 * Cc) + h * 192 + which * 64) * Tt + t0;
  const int dl = tid >> 2, j16 = (tid & 3) * 16;
  const u16x8 a0 = *(const u16x8*)(src + (size_t)dl * Tt + j16);
  const u16x8 a1 = *(const u16x8*)(src + (size_t)dl * Tt + j16 + 8);
#pragma unroll
  for (int q = 0; q < 8; ++q) Tl[j16 + q][dl] = a0[q];
#pragma unroll
  for (int q = 0; q < 8; ++q) Tl[j16 + 8 + q][dl] = a1[q];
  __syncthreads();
  const int tl = tid >> 2, i16 = (tid & 3) * 16;
  unsigned short* dst = qkt + ((size_t)bhw * Tt + t0 + tl) * 64 + i16;
  *(u16x8*)dst = *(const u16x8*)&Tl[tl][i16];
  *(u16x8*)(dst + 8) = *(const u16x8*)&Tl[tl][i16 + 8];
}

// ---------------------------------------------------------------------------
// K5: bf16 MFMA GEMM, m97 structure. out[z][m][n] = A[m][:]·Bt[z][n][:] + bias
// BM=BN=128, BK=32, 256 thr (4 waves, 2x2 of 64x64), global_load_lds 16B.
// MODE 0: write bf16 (qkv). MODE 1: write fp32 + residual (proj).
// ---------------------------------------------------------------------------
template <int MODE>
__global__ __launch_bounds__(256) void gemm_mfma(const unsigned short* __restrict__ A,
                                                 const unsigned short* __restrict__ Bt,
                                                 const float* __restrict__ bias,
                                                 const float* __restrict__ res,
                                                 unsigned short* __restrict__ outb,
                                                 float* __restrict__ outf, int M) {
  __shared__ unsigned short Al[128 * 32];
  __shared__ unsigned short Bl[128 * 32];
  const int tid = threadIdx.x;
  const int n0 = blockIdx.x * 128, m0 = blockIdx.y * 128;
  const size_t z = blockIdx.z;
  const int l = tid & 63, il = l & 15, g = l >> 4;
  const int w = tid >> 6;
  const int wm = (w >> 1) * 64, wn = (w & 1) * 64;

  const unsigned short* Bz = Bt + z * (size_t)Tt * Cc;
  const unsigned short* Ap = A + (size_t)(m0 + (tid >> 2)) * Cc + (tid & 3) * 8;
  const unsigned short* Bp = Bz + (size_t)(n0 + (tid >> 2)) * Cc + (tid & 3) * 8;
  char* ldsA = (char*)Al + w * 1024;  // wave-uniform dest base
  char* ldsB = (char*)Bl + w * 1024;

  f32x4 acc[4][4] = {};
  for (int k0 = 0; k0 < Cc; k0 += 32) {
    async16(Ap + k0, ldsA);
    async16(Ap + (size_t)64 * Cc + k0, ldsA + 4096);
    async16(Bp + k0, ldsB);
    async16(Bp + (size_t)64 * Cc + k0, ldsB + 4096);
    __syncthreads();
    short8 af[4], bf[4];
#pragma unroll
    for (int i = 0; i < 4; ++i)
      af[i] = *(const short8*)(Al + (wm + i * 16 + il) * 32 + g * 8);
#pragma unroll
    for (int j = 0; j < 4; ++j)
      bf[j] = *(const short8*)(Bl + (wn + j * 16 + il) * 32 + g * 8);
#pragma unroll
    for (int i = 0; i < 4; ++i)
#pragma unroll
      for (int j = 0; j < 4; ++j)
        acc[i][j] = __builtin_amdgcn_mfma_f32_16x16x32_bf16(af[i], bf[j], acc[i][j], 0, 0, 0);
    __syncthreads();
  }

#pragma unroll
  for (int i = 0; i < 4; ++i) {
#pragma unroll
    for (int r = 0; r < 4; ++r) {
      const int m = m0 + wm + i * 16 + 4 * g + r;
      const float bv = bias[m];
#pragma unroll
      for (int j = 0; j < 4; ++j) {
        const int n = n0 + wn + j * 16 + il;
        const float v = acc[i][j][r] + bv;
        const size_t idx = (z * (size_t)M + m) * Tt + n;
        if (MODE == 0) {
          outb[idx] = f2bf(v);
        } else {
          outf[idx] = v + res[idx];
        }
      }
    }
  }
}

// ---------------------------------------------------------------------------
// K6: MFMA flash attention. Block = (q-tile 64, b*8+h); 4 waves, 16 q each.
// S^T = mfma(K, Q) so each lane owns one q-row (swapped trick); softmax in
// regs; P -> LDS bf16; PV = mfma(P, V). V kept channel-major [d][s].
// Output token-major attnoT[b][t][c] bf16 (feeds proj GEMM as B^T).
// ---------------------------------------------------------------------------
__global__ __launch_bounds__(256) void attn_mfma(const unsigned short* __restrict__ qkt,
                                                 const unsigned short* __restrict__ qkvc,
                                                 unsigned short* __restrict__ attnoT) {
  __shared__ unsigned short Kl[64][72];  // [s][d] token-major, 144B rows
  __shared__ unsigned short Vl[64][72];  // [d][s] channel-major
  __shared__ unsigned short Pl[64][72];  // [q][s] bf16 probabilities
  const int tid = threadIdx.x;
  const int w = tid >> 6, l = tid & 63, il = l & 15, g = l >> 4;
  const int bh = blockIdx.y, q0 = blockIdx.x * 64;
  const int b = bh >> 3, h = bh & 7;
  const unsigned short* Qb = qkt + (size_t)(bh * 2) * Tt * 64;
  const unsigned short* Kb = Qb + (size_t)Tt * 64;
  const unsigned short* Vb = qkvc + ((size_t)b * (3 * Cc) + h * 192 + 128) * Tt;

  // Q fragments (B-operand): col q = q0 + w*16 + il, k = d contiguous
  short8 qf[2];
  {
    const unsigned short* qp = Qb + (size_t)(q0 + w * 16 + il) * 64 + g * 8;
    qf[0] = *(const short8*)qp;
    qf[1] = *(const short8*)(qp + 32);
  }
  float m_run = -1e30f, l_run = 0.f;
  f32x4 acco[4] = {};  // O[q=4g+r][d=j*16+il]

  const int rr0 = tid >> 3;       // 0..31 staging row
  const int sc = (tid & 7) * 8;   // staging col (8 bf16)

  for (int s0 = 0; s0 < Tt; s0 += 64) {
#pragma unroll
    for (int p = 0; p < 2; ++p) {
      const int rr = p * 32 + rr0;
      *(uint4*)&Kl[rr][sc] = *(const uint4*)(Kb + (size_t)(s0 + rr) * 64 + sc);
      *(uint4*)&Vl[rr][sc] = *(const uint4*)(Vb + (size_t)rr * Tt + s0 + sc);
    }
    __syncthreads();

    // S^T = K·Q^T : rows s (4 frags), cols q (wave strip)
    f32x4 accs[4] = {};
#pragma unroll
    for (int ks = 0; ks < 2; ++ks) {
#pragma unroll
      for (int i = 0; i < 4; ++i) {
        const short8 kf = *(const short8*)&Kl[i * 16 + il][ks * 32 + g * 8];
        accs[i] = __builtin_amdgcn_mfma_f32_16x16x32_bf16(kf, qf[ks], accs[i], 0, 0, 0);
      }
    }

    // Online softmax for row q = w*16+il (16 owned vals + 2 shfl_xor)
    float sv[4][4];
    float mx = -1e30f;
#pragma unroll
    for (int i = 0; i < 4; ++i)
#pragma unroll
      for (int r = 0; r < 4; ++r) {
        const float t = accs[i][r] * 0.125f;  // scale^2 = 1/sqrt(dh)
        sv[i][r] = t;
        mx = fmaxf(mx, t);
      }
    mx = fmaxf(mx, __shfl_xor(mx, 16));
    mx = fmaxf(mx, __shfl_xor(mx, 32));
    const float mnew = fmaxf(m_run, mx);
    float rsum = 0.f;
#pragma unroll
    for (int i = 0; i < 4; ++i) {
      float p0 = __expf(sv[i][0] - mnew);
      float p1 = __expf(sv[i][1] - mnew);
      float p2 = __expf(sv[i][2] - mnew);
      float p3 = __expf(sv[i][3] - mnew);
      rsum += p0 + p1 + p2 + p3;
      ushort4 pk;
      pk.x = f2bf(p0); pk.y = f2bf(p1); pk.z = f2bf(p2); pk.w = f2bf(p3);
      *(ushort4*)&Pl[w * 16 + il][i * 16 + g * 4] = pk;  // s = i*16+4g+r
    }
    rsum += __shfl_xor(rsum, 16);
    rsum += __shfl_xor(rsum, 32);
    const float alpha = __expf(m_run - mnew);
    l_run = l_run * alpha + rsum;
    m_run = mnew;
    __syncthreads();

    // Rescale O by alpha of its rows (q = 4g+r), fetched by intra-wave shfl
    float ar[4];
#pragma unroll
    for (int r = 0; r < 4; ++r) ar[r] = __shfl(alpha, 4 * g + r);
#pragma unroll
    for (int j = 0; j < 4; ++j) {
      f32x4 t = acco[j];
      t[0] *= ar[0]; t[1] *= ar[1]; t[2] *= ar[2]; t[3] *= ar[3];
      acco[j] = t;
    }
    // O += P·V
#pragma unroll
    for (int ks = 0; ks < 2; ++ks) {
      const short8 pf = *(const short8*)&Pl[w * 16 + il][ks * 32 + g * 8];
#pragma unroll
      for (int j = 0; j < 4; ++j) {
        const short8 vf = *(const short8*)&Vl[j * 16 + il][ks * 32 + g * 8];
        acco[j] = __builtin_amdgcn_mfma_f32_16x16x32_bf16(pf, vf, acco[j], 0, 0, 0);
      }
    }
    __syncthreads();
  }

  // Epilogue: divide by l, write token-major bf16
  float linv[4];
#pragma unroll
  for (int r = 0; r < 4; ++r) linv[r] = 1.f / __shfl(l_run, 4 * g + r);
#pragma unroll
  for (int r = 0; r < 4; ++r) {
    const int t = q0 + w * 16 + 4 * g + r;
    unsigned short* dst = attnoT + ((size_t)b * Tt + t) * Cc + h * 64 + il;
#pragma unroll
    for (int j = 0; j < 4; ++j) dst[j * 16] = f2bf(acco[j][r] * linv[r]);
  }
}

// ---------------------------------------------------------------------------
extern "C" void kernel_launch(void* const* d_in, const int* in_sizes, int n_in,
                              void* d_out, int out_size, void* d_ws, size_t ws_size,
                              hipStream_t stream) {
  const float* x = (const float*)d_in[0];
  const float* gamma = (const float*)d_in[1];
  const float* beta = (const float*)d_in[2];
  const float* w_qkv = (const float*)d_in[3];
  const float* b_qkv = (const float*)d_in[4];
  const float* w_proj = (const float*)d_in[5];
  const float* b_proj = (const float*)d_in[6];
  float* out = (float*)d_out;

  // Workspace carve (bytes, 256-aligned)
  char* p = (char*)d_ws;
  float* stats = (float*)p;                 p += 256 * sizeof(float);
  unsigned short* hT = (unsigned short*)p;  p += (size_t)Bb * Tt * Cc * 2;          // 8 MB
  unsigned short* wq = (unsigned short*)p;  p += (size_t)3 * Cc * Cc * 2;           // 1.5 MB
  unsigned short* wp = (unsigned short*)p;  p += (size_t)Cc * Cc * 2;               // 0.5 MB
  unsigned short* qkvc = (unsigned short*)p; p += (size_t)Bb * 3 * Cc * Tt * 2;     // 25 MB
  unsigned short* qkt = (unsigned short*)p; p += (size_t)Bb * Hh * 2 * Tt * 64 * 2; // 17 MB
  unsigned short* attnoT = (unsigned short*)p;                                      // 8 MB

  gn_stats<<<dim3(Bb * 32), 256, 0, stream>>>(x, stats);
  norm_trans<<<dim3(Tt / 64, Cc / 64, Bb), 256, 0, stream>>>(x, stats, gamma, beta, hT);
  cvt_bf16<<<dim3((3 * Cc * Cc / 4 + 255) / 256), 256, 0, stream>>>(w_qkv, wq, 3 * Cc * Cc / 4);
  cvt_bf16<<<dim3((Cc * Cc / 4 + 255) / 256), 256, 0, stream>>>(w_proj, wp, Cc * Cc / 4);
  gemm_mfma<0><<<dim3(Tt / 128, (3 * Cc) / 128, Bb), 256, 0, stream>>>(
      wq, hT, b_qkv, nullptr, qkvc, nullptr, 3 * Cc);
  qk_trans<<<dim3(Tt / 64, Bb * Hh * 2), 256, 0, stream>>>(qkvc, qkt);
  attn_mfma<<<dim3(Tt / 64, Bb * Hh), 256, 0, stream>>>(qkt, qkvc, attnoT);
  gemm_mfma<1><<<dim3(Tt / 128, Cc / 128, Bb), 256, 0, stream>>>(
      wp, attnoT, b_proj, x, nullptr, out, Cc);
}

// Round 3
// 145.808 us; speedup vs baseline: 6.2863x; 1.1419x over previous
//
#include <hip/hip_runtime.h>
#include <hip/hip_bf16.h>
#include <math.h>
#include <stdint.h>

// Problem constants: B=4, C=512, T=2048, H=8, dh=64, G=32
#define Bb 4
#define Cc 512
#define Tt 2048
#define Hh 8

typedef __attribute__((ext_vector_type(8))) short short8;   // 8 bf16 (4 VGPR) MFMA operand
typedef __attribute__((ext_vector_type(4))) float f32x4;    // MFMA accumulator
typedef __attribute__((ext_vector_type(8))) unsigned short u16x8;

__device__ __forceinline__ unsigned short f2bf(float f) {   // native cvt (fuses to cvt_pk)
  __hip_bfloat16 h = __float2bfloat16(f);
  unsigned short u;
  __builtin_memcpy(&u, &h, 2);
  return u;
}
__device__ __forceinline__ float bf2f(unsigned short u) {
  union { uint32_t i; float f; } v;
  v.i = (uint32_t)u << 16;
  return v.f;
}

__device__ __forceinline__ void async16(const void* g, void* l) {
  __builtin_amdgcn_global_load_lds(
      (const __attribute__((address_space(1))) uint32_t*)g,
      (__attribute__((address_space(3))) uint32_t*)l, 16, 0, 0);
}

// ---------------------------------------------------------------------------
// K1: per-(b,group) mean/rstd.
// ---------------------------------------------------------------------------
__global__ __launch_bounds__(256) void gn_stats(const float* __restrict__ x,
                                                float* __restrict__ stats) {
  const int blk = blockIdx.x;
  const size_t base = (size_t)blk * 16 * Tt;
  const int N = 16 * Tt;
  const int tid = threadIdx.x;
  float s = 0.f, ss = 0.f;
  for (int i = tid * 4; i < N; i += 1024) {
    const float4 v = *(const float4*)(x + base + i);
    s += v.x + v.y + v.z + v.w;
    ss += v.x * v.x + v.y * v.y + v.z * v.z + v.w * v.w;
  }
#pragma unroll
  for (int off = 32; off >= 1; off >>= 1) {
    s += __shfl_down(s, off);
    ss += __shfl_down(ss, off);
  }
  __shared__ float rs[4], rss[4];
  const int wid = tid >> 6;
  if ((tid & 63) == 0) { rs[wid] = s; rss[wid] = ss; }
  __syncthreads();
  if (tid == 0) {
    const float a = rs[0] + rs[1] + rs[2] + rs[3];
    const float c = rss[0] + rss[1] + rss[2] + rss[3];
    const float mean = a / (float)N;
    const float var = c / (float)N - mean * mean;
    stats[blk * 2] = mean;
    stats[blk * 2 + 1] = rsqrtf(var + 1e-5f);
  }
}

// ---------------------------------------------------------------------------
// K2: normalize + convert + transpose: x fp32 [b][c][t] -> hT bf16 [b][t][c].
// ---------------------------------------------------------------------------
__global__ __launch_bounds__(256) void norm_trans(const float* __restrict__ x,
                                                  const float* __restrict__ stats,
                                                  const float* __restrict__ gamma,
                                                  const float* __restrict__ beta,
                                                  unsigned short* __restrict__ hT) {
  __shared__ unsigned short Tl[64][72];
  const int tid = threadIdx.x;
  const int b = blockIdx.z, c0 = blockIdx.y * 64, t0 = blockIdx.x * 64;
  const int cl = tid >> 2, j16 = (tid & 3) * 16;
  const int c = c0 + cl;
  const int grp = c >> 4;
  const float mean = stats[((size_t)b * 32 + grp) * 2];
  const float rstd = stats[((size_t)b * 32 + grp) * 2 + 1];
  const float ga = gamma[c] * rstd;
  const float be = beta[c] - mean * ga;
  const float* src = x + ((size_t)b * Cc + c) * Tt + t0 + j16;
#pragma unroll
  for (int q = 0; q < 4; ++q) {
    const float4 v = *(const float4*)(src + q * 4);
    Tl[j16 + q * 4 + 0][cl] = f2bf(v.x * ga + be);
    Tl[j16 + q * 4 + 1][cl] = f2bf(v.y * ga + be);
    Tl[j16 + q * 4 + 2][cl] = f2bf(v.z * ga + be);
    Tl[j16 + q * 4 + 3][cl] = f2bf(v.w * ga + be);
  }
  __syncthreads();
  const int tl = tid >> 2, i16 = (tid & 3) * 16;
  unsigned short* dst = hT + ((size_t)b * Tt + t0 + tl) * Cc + c0 + i16;
  *(u16x8*)dst = *(const u16x8*)&Tl[tl][i16];
  *(u16x8*)(dst + 8) = *(const u16x8*)&Tl[tl][i16 + 8];
}

// ---------------------------------------------------------------------------
// K3: fp32 -> bf16 convert (weights).
// ---------------------------------------------------------------------------
__global__ __launch_bounds__(256) void cvt_bf16(const float* __restrict__ in,
                                                unsigned short* __restrict__ out, int n4) {
  const int i = blockIdx.x * 256 + threadIdx.x;
  if (i < n4) {
    const float4 v = *(const float4*)(in + (size_t)i * 4);
    ushort4 o;
    o.x = f2bf(v.x); o.y = f2bf(v.y); o.z = f2bf(v.z); o.w = f2bf(v.w);
    *(ushort4*)(out + (size_t)i * 4) = o;
  }
}

// ---------------------------------------------------------------------------
// K4: bf16 transpose 64x64: qkv [b][3C][t] (Q,K) -> qkt [(bh*2+w)][t][64].
// Q (which==0) pre-scaled by 1/8 (power of 2 -> exact in bf16).
// ---------------------------------------------------------------------------
__global__ __launch_bounds__(256) void qk_trans(const unsigned short* __restrict__ qkv,
                                                unsigned short* __restrict__ qkt) {
  __shared__ unsigned short Tl[64][72];
  const int tid = threadIdx.x;
  const int t0 = blockIdx.x * 64;
  const int bhw = blockIdx.y;  // (b*8+h)*2 + which
  const int b = bhw >> 4, hw = bhw & 15;
  const int h = hw >> 1, which = hw & 1;
  const unsigned short* src =
      qkv + ((size_t)b * (3 * Cc) + h * 192 + which * 64) * Tt + t0;
  const int dl = tid >> 2, j16 = (tid & 3) * 16;
  u16x8 a0 = *(const u16x8*)(src + (size_t)dl * Tt + j16);
  u16x8 a1 = *(const u16x8*)(src + (size_t)dl * Tt + j16 + 8);
  if (which == 0) {
#pragma unroll
    for (int q = 0; q < 8; ++q) {
      a0[q] = f2bf(bf2f(a0[q]) * 0.125f);
      a1[q] = f2bf(bf2f(a1[q]) * 0.125f);
    }
  }
#pragma unroll
  for (int q = 0; q < 8; ++q) Tl[j16 + q][dl] = a0[q];
#pragma unroll
  for (int q = 0; q < 8; ++q) Tl[j16 + 8 + q][dl] = a1[q];
  __syncthreads();
  const int tl = tid >> 2, i16 = (tid & 3) * 16;
  unsigned short* dst = qkt + ((size_t)bhw * Tt + t0 + tl) * 64 + i16;
  *(u16x8*)dst = *(const u16x8*)&Tl[tl][i16];
  *(u16x8*)(dst + 8) = *(const u16x8*)&Tl[tl][i16 + 8];
}

// ---------------------------------------------------------------------------
// K5: bf16 MFMA GEMM (m97 structure), BM=BN=128, BK=32, 4 waves.
// ---------------------------------------------------------------------------
template <int MODE>
__global__ __launch_bounds__(256) void gemm_mfma(const unsigned short* __restrict__ A,
                                                 const unsigned short* __restrict__ Bt,
                                                 const float* __restrict__ bias,
                                                 const float* __restrict__ res,
                                                 unsigned short* __restrict__ outb,
                                                 float* __restrict__ outf, int M) {
  __shared__ unsigned short Al[128 * 32];
  __shared__ unsigned short Bl[128 * 32];
  const int tid = threadIdx.x;
  const int n0 = blockIdx.x * 128, m0 = blockIdx.y * 128;
  const size_t z = blockIdx.z;
  const int l = tid & 63, il = l & 15, g = l >> 4;
  const int w = tid >> 6;
  const int wm = (w >> 1) * 64, wn = (w & 1) * 64;

  const unsigned short* Bz = Bt + z * (size_t)Tt * Cc;
  const unsigned short* Ap = A + (size_t)(m0 + (tid >> 2)) * Cc + (tid & 3) * 8;
  const unsigned short* Bp = Bz + (size_t)(n0 + (tid >> 2)) * Cc + (tid & 3) * 8;
  char* ldsA = (char*)Al + w * 1024;
  char* ldsB = (char*)Bl + w * 1024;

  f32x4 acc[4][4] = {};
  for (int k0 = 0; k0 < Cc; k0 += 32) {
    async16(Ap + k0, ldsA);
    async16(Ap + (size_t)64 * Cc + k0, ldsA + 4096);
    async16(Bp + k0, ldsB);
    async16(Bp + (size_t)64 * Cc + k0, ldsB + 4096);
    __syncthreads();
    short8 af[4], bf[4];
#pragma unroll
    for (int i = 0; i < 4; ++i)
      af[i] = *(const short8*)(Al + (wm + i * 16 + il) * 32 + g * 8);
#pragma unroll
    for (int j = 0; j < 4; ++j)
      bf[j] = *(const short8*)(Bl + (wn + j * 16 + il) * 32 + g * 8);
    __builtin_amdgcn_s_setprio(1);
#pragma unroll
    for (int i = 0; i < 4; ++i)
#pragma unroll
      for (int j = 0; j < 4; ++j)
        acc[i][j] = __builtin_amdgcn_mfma_f32_16x16x32_bf16(af[i], bf[j], acc[i][j], 0, 0, 0);
    __builtin_amdgcn_s_setprio(0);
    __syncthreads();
  }

#pragma unroll
  for (int i = 0; i < 4; ++i) {
#pragma unroll
    for (int r = 0; r < 4; ++r) {
      const int m = m0 + wm + i * 16 + 4 * g + r;
      const float bv = bias[m];
#pragma unroll
      for (int j = 0; j < 4; ++j) {
        const int n = n0 + wn + j * 16 + il;
        const float v = acc[i][j][r] + bv;
        const size_t idx = (z * (size_t)M + m) * Tt + n;
        if (MODE == 0) {
          outb[idx] = f2bf(v);
        } else {
          outf[idx] = v + res[idx];
        }
      }
    }
  }
}

// ---------------------------------------------------------------------------
// K6: MFMA flash attention v2.
// Block = 256 thr (4 waves), QBLK=128 (wave w owns q rows w*32..w*32+31 as two
// 16-col strips), KVBLK=64, K/V double-buffered in LDS via global_load_lds
// with XOR-swizzled per-lane SOURCE addresses (LDS linear, pitch 128B; read
// col16 = (ks*4+g)^(il&7) -> 2-way max). One barrier per iter (T3 2-phase).
// P round-trip through LDS is intra-wave (lgkmcnt only, no barrier).
// Grid: 512 blocks flat, XCD-swizzled (16 q-tiles of one head per XCD).
// ---------------------------------------------------------------------------
__global__ __launch_bounds__(256) void attn_mfma2(const unsigned short* __restrict__ qkt,
                                                  const unsigned short* __restrict__ qkvc,
                                                  unsigned short* __restrict__ attnoT) {
  __shared__ unsigned short KVs[2][2][64 * 64];  // [buf][K/V][row*64+col] swizzled
  __shared__ unsigned short Pl[128][72];         // [q][s] bf16, padded pitch

  const int tid = threadIdx.x;
  const int w = tid >> 6, l = tid & 63, il = l & 15, g = l >> 4;

  // XCD-aware swizzle of flat 512-block grid (512 % 8 == 0 -> bijective)
  const int bid = blockIdx.x;
  const int swz = (bid & 7) * 64 + (bid >> 3);
  const int bh = swz >> 4, qt = swz & 15;
  const int b = bh >> 3, h = bh & 7;
  const int q0 = qt * 128;

  const unsigned short* Qb = qkt + (size_t)(bh * 2) * Tt * 64;
  const char* Kb = (const char*)(Qb + (size_t)Tt * 64);
  const char* Vb = (const char*)(qkvc + ((size_t)b * (3 * Cc) + h * 192 + 128) * Tt);

  // Q fragments (B-operand, token-major, pre-scaled by 1/8 in qk_trans)
  short8 qf0[2], qf1[2];
  {
    const unsigned short* qp0 = Qb + (size_t)(q0 + w * 32 + il) * 64 + g * 8;
    qf0[0] = *(const short8*)qp0;
    qf0[1] = *(const short8*)(qp0 + 32);
    const unsigned short* qp1 = qp0 + 16 * 64;
    qf1[0] = *(const short8*)qp1;
    qf1[1] = *(const short8*)(qp1 + 32);
  }

  float m0r = -1e30f, m1r = -1e30f, l0r = 0.f, l1r = 0.f;
  f32x4 acco0[4] = {}, acco1[4] = {};

  // staging geometry: wave w covers rows w*16..w*16+15 (two 1KB calls each
  // for K and V); lane deposits 16B at linear (row, (l&7)*16); source col is
  // pre-swizzled so LDS holds col' = col ^ ((row&7)<<4).
  const int srow = w * 16 + (l >> 3);
  const int scol = ((l & 7) ^ (l >> 3)) << 4;

  auto stage = [&](int buf, int s0) {
    char* kd = (char*)&KVs[buf][0][0] + w * 2048;
    char* vd = (char*)&KVs[buf][1][0] + w * 2048;
    async16(Kb + (size_t)(s0 + srow) * 128 + scol, kd);
    async16(Kb + (size_t)(s0 + srow + 8) * 128 + scol, kd + 1024);
    async16(Vb + (size_t)srow * (Tt * 2) + (size_t)s0 * 2 + scol, vd);
    async16(Vb + (size_t)(srow + 8) * (Tt * 2) + (size_t)s0 * 2 + scol, vd + 1024);
  };

  stage(0, 0);
  __syncthreads();
  int cur = 0;

  const int NT = Tt / 64;
  for (int t = 0; t < NT; ++t) {
    if (t + 1 < NT) stage(cur ^ 1, (t + 1) * 64);
    const unsigned short* Kc = &KVs[cur][0][0];
    const unsigned short* Vc = &KVs[cur][1][0];

    // S^T = K·Q^T (shared kf across both q-strips)
    f32x4 accs0[4] = {}, accs1[4] = {};
    __builtin_amdgcn_s_setprio(1);
#pragma unroll
    for (int ks = 0; ks < 2; ++ks) {
#pragma unroll
      for (int i = 0; i < 4; ++i) {
        const short8 kf =
            *(const short8*)(Kc + (i * 16 + il) * 64 + ((((ks << 2) + g) ^ (il & 7)) << 3));
        accs0[i] = __builtin_amdgcn_mfma_f32_16x16x32_bf16(kf, qf0[ks], accs0[i], 0, 0, 0);
        accs1[i] = __builtin_amdgcn_mfma_f32_16x16x32_bf16(kf, qf1[ks], accs1[i], 0, 0, 0);
      }
    }
    __builtin_amdgcn_s_setprio(0);

    // Online softmax, strip 0 (lane owns q-row w*32+il; 15 fmax + 2 shfl)
    float a0, a1;
    {
      float mx = -1e30f;
#pragma unroll
      for (int i = 0; i < 4; ++i)
#pragma unroll
        for (int r = 0; r < 4; ++r) mx = fmaxf(mx, accs0[i][r]);
      mx = fmaxf(mx, __shfl_xor(mx, 16));
      mx = fmaxf(mx, __shfl_xor(mx, 32));
      const float mnew = fmaxf(m0r, mx);
      float rsum = 0.f;
      unsigned short* prow = &Pl[w * 32 + il][0];
#pragma unroll
      for (int i = 0; i < 4; ++i) {
        const float p0 = __expf(accs0[i][0] - mnew);
        const float p1 = __expf(accs0[i][1] - mnew);
        const float p2 = __expf(accs0[i][2] - mnew);
        const float p3 = __expf(accs0[i][3] - mnew);
        rsum += p0 + p1 + p2 + p3;
        ushort4 pk;
        pk.x = f2bf(p0); pk.y = f2bf(p1); pk.z = f2bf(p2); pk.w = f2bf(p3);
        *(ushort4*)(prow + i * 16 + g * 4) = pk;
      }
      rsum += __shfl_xor(rsum, 16);
      rsum += __shfl_xor(rsum, 32);
      a0 = __expf(m0r - mnew);
      l0r = l0r * a0 + rsum;
      m0r = mnew;
    }
    // strip 1 (q-row w*32+16+il)
    {
      float mx = -1e30f;
#pragma unroll
      for (int i = 0; i < 4; ++i)
#pragma unroll
        for (int r = 0; r < 4; ++r) mx = fmaxf(mx, accs1[i][r]);
      mx = fmaxf(mx, __shfl_xor(mx, 16));
      mx = fmaxf(mx, __shfl_xor(mx, 32));
      const float mnew = fmaxf(m1r, mx);
      float rsum = 0.f;
      unsigned short* prow = &Pl[w * 32 + 16 + il][0];
#pragma unroll
      for (int i = 0; i < 4; ++i) {
        const float p0 = __expf(accs1[i][0] - mnew);
        const float p1 = __expf(accs1[i][1] - mnew);
        const float p2 = __expf(accs1[i][2] - mnew);
        const float p3 = __expf(accs1[i][3] - mnew);
        rsum += p0 + p1 + p2 + p3;
        ushort4 pk;
        pk.x = f2bf(p0); pk.y = f2bf(p1); pk.z = f2bf(p2); pk.w = f2bf(p3);
        *(ushort4*)(prow + i * 16 + g * 4) = pk;
      }
      rsum += __shfl_xor(rsum, 16);
      rsum += __shfl_xor(rsum, 32);
      a1 = __expf(m1r - mnew);
      l1r = l1r * a1 + rsum;
      m1r = mnew;
    }

    // make P visible to this wave's ds_reads (intra-wave only; no barrier)
    asm volatile("s_waitcnt lgkmcnt(0)" ::: "memory");

    // rescale O by per-row alpha
    float ar0[4], ar1[4];
#pragma unroll
    for (int r = 0; r < 4; ++r) {
      ar0[r] = __shfl(a0, 4 * g + r);
      ar1[r] = __shfl(a1, 4 * g + r);
    }
#pragma unroll
    for (int j = 0; j < 4; ++j) {
      f32x4 t0 = acco0[j], t1 = acco1[j];
      t0[0] *= ar0[0]; t0[1] *= ar0[1]; t0[2] *= ar0[2]; t0[3] *= ar0[3];
      t1[0] *= ar1[0]; t1[1] *= ar1[1]; t1[2] *= ar1[2]; t1[3] *= ar1[3];
      acco0[j] = t0; acco1[j] = t1;
    }

    // O += P·V (shared vf across strips)
    __builtin_amdgcn_s_setprio(1);
#pragma unroll
    for (int ks = 0; ks < 2; ++ks) {
      const short8 pf0 = *(const short8*)(&Pl[w * 32 + il][ks * 32 + g * 8]);
      const short8 pf1 = *(const short8*)(&Pl[w * 32 + 16 + il][ks * 32 + g * 8]);
#pragma unroll
      for (int j = 0; j < 4; ++j) {
        const short8 vf =
            *(const short8*)(Vc + (j * 16 + il) * 64 + ((((ks << 2) + g) ^ (il & 7)) << 3));
        acco0[j] = __builtin_amdgcn_mfma_f32_16x16x32_bf16(pf0, vf, acco0[j], 0, 0, 0);
        acco1[j] = __builtin_amdgcn_mfma_f32_16x16x32_bf16(pf1, vf, acco1[j], 0, 0, 0);
      }
    }
    __builtin_amdgcn_s_setprio(0);

    __syncthreads();  // all waves done with cur; next-tile loads drained
    cur ^= 1;
  }

  // Epilogue: divide by l, write token-major bf16
#pragma unroll
  for (int r = 0; r < 4; ++r) {
    const float li0 = 1.f / __shfl(l0r, 4 * g + r);
    const float li1 = 1.f / __shfl(l1r, 4 * g + r);
    const int t0r = q0 + w * 32 + 4 * g + r;
    unsigned short* d0 = attnoT + ((size_t)b * Tt + t0r) * Cc + h * 64 + il;
    unsigned short* d1 = attnoT + ((size_t)b * Tt + t0r + 16) * Cc + h * 64 + il;
#pragma unroll
    for (int j = 0; j < 4; ++j) {
      d0[j * 16] = f2bf(acco0[j][r] * li0);
      d1[j * 16] = f2bf(acco1[j][r] * li1);
    }
  }
}

// ---------------------------------------------------------------------------
extern "C" void kernel_launch(void* const* d_in, const int* in_sizes, int n_in,
                              void* d_out, int out_size, void* d_ws, size_t ws_size,
                              hipStream_t stream) {
  const float* x = (const float*)d_in[0];
  const float* gamma = (const float*)d_in[1];
  const float* beta = (const float*)d_in[2];
  const float* w_qkv = (const float*)d_in[3];
  const float* b_qkv = (const float*)d_in[4];
  const float* w_proj = (const float*)d_in[5];
  const float* b_proj = (const float*)d_in[6];
  float* out = (float*)d_out;

  char* p = (char*)d_ws;
  float* stats = (float*)p;                  p += 256 * sizeof(float);
  unsigned short* hT = (unsigned short*)p;   p += (size_t)Bb * Tt * Cc * 2;
  unsigned short* wq = (unsigned short*)p;   p += (size_t)3 * Cc * Cc * 2;
  unsigned short* wp = (unsigned short*)p;   p += (size_t)Cc * Cc * 2;
  unsigned short* qkvc = (unsigned short*)p; p += (size_t)Bb * 3 * Cc * Tt * 2;
  unsigned short* qkt = (unsigned short*)p;  p += (size_t)Bb * Hh * 2 * Tt * 64 * 2;
  unsigned short* attnoT = (unsigned short*)p;

  gn_stats<<<dim3(Bb * 32), 256, 0, stream>>>(x, stats);
  norm_trans<<<dim3(Tt / 64, Cc / 64, Bb), 256, 0, stream>>>(x, stats, gamma, beta, hT);
  cvt_bf16<<<dim3((3 * Cc * Cc / 4 + 255) / 256), 256, 0, stream>>>(w_qkv, wq, 3 * Cc * Cc / 4);
  cvt_bf16<<<dim3((Cc * Cc / 4 + 255) / 256), 256, 0, stream>>>(w_proj, wp, Cc * Cc / 4);
  gemm_mfma<0><<<dim3(Tt / 128, (3 * Cc) / 128, Bb), 256, 0, stream>>>(
      wq, hT, b_qkv, nullptr, qkvc, nullptr, 3 * Cc);
  qk_trans<<<dim3(Tt / 64, Bb * Hh * 2), 256, 0, stream>>>(qkvc, qkt);
  attn_mfma2<<<dim3(512), 256, 0, stream>>>(qkt, qkvc, attnoT);
  gemm_mfma<1><<<dim3(Tt / 128, Cc / 128, Bb), 256, 0, stream>>>(
      wp, attnoT, b_proj, x, nullptr, out, Cc);
}

// Round 4
// 129.016 us; speedup vs baseline: 7.1045x; 1.1302x over previous
//
#include <hip/hip_runtime.h>
#include <hip/hip_bf16.h>
#include <math.h>
#include <stdint.h>

// Problem constants: B=4, C=512, T=2048, H=8, dh=64, G=32
#define Bb 4
#define Cc 512
#define Tt 2048
#define Hh 8

typedef __attribute__((ext_vector_type(8))) short short8;   // 8 bf16 (4 VGPR) MFMA operand
typedef __attribute__((ext_vector_type(4))) float f32x4;    // MFMA accumulator
typedef __attribute__((ext_vector_type(8))) unsigned short u16x8;

__device__ __forceinline__ unsigned short f2bf(float f) {
  __hip_bfloat16 h = __float2bfloat16(f);
  unsigned short u;
  __builtin_memcpy(&u, &h, 2);
  return u;
}
__device__ __forceinline__ float bf2f(unsigned short u) {
  union { uint32_t i; float f; } v;
  v.i = (uint32_t)u << 16;
  return v.f;
}

__device__ __forceinline__ void async16(const void* g, void* l) {
  __builtin_amdgcn_global_load_lds(
      (const __attribute__((address_space(1))) uint32_t*)g,
      (__attribute__((address_space(3))) uint32_t*)l, 16, 0, 0);
}

// ---------------------------------------------------------------------------
// K1: per-(b,group) mean/rstd.
// ---------------------------------------------------------------------------
__global__ __launch_bounds__(256) void gn_stats(const float* __restrict__ x,
                                                float* __restrict__ stats) {
  const int blk = blockIdx.x;
  const size_t base = (size_t)blk * 16 * Tt;
  const int N = 16 * Tt;
  const int tid = threadIdx.x;
  float s = 0.f, ss = 0.f;
  for (int i = tid * 4; i < N; i += 1024) {
    const float4 v = *(const float4*)(x + base + i);
    s += v.x + v.y + v.z + v.w;
    ss += v.x * v.x + v.y * v.y + v.z * v.z + v.w * v.w;
  }
#pragma unroll
  for (int off = 32; off >= 1; off >>= 1) {
    s += __shfl_down(s, off);
    ss += __shfl_down(ss, off);
  }
  __shared__ float rs[4], rss[4];
  const int wid = tid >> 6;
  if ((tid & 63) == 0) { rs[wid] = s; rss[wid] = ss; }
  __syncthreads();
  if (tid == 0) {
    const float a = rs[0] + rs[1] + rs[2] + rs[3];
    const float c = rss[0] + rss[1] + rss[2] + rss[3];
    const float mean = a / (float)N;
    const float var = c / (float)N - mean * mean;
    stats[blk * 2] = mean;
    stats[blk * 2 + 1] = rsqrtf(var + 1e-5f);
  }
}

// ---------------------------------------------------------------------------
// K2: normalize + convert + transpose: x fp32 [b][c][t] -> hT bf16 [b][t][c].
// ---------------------------------------------------------------------------
__global__ __launch_bounds__(256) void norm_trans(const float* __restrict__ x,
                                                  const float* __restrict__ stats,
                                                  const float* __restrict__ gamma,
                                                  const float* __restrict__ beta,
                                                  unsigned short* __restrict__ hT) {
  __shared__ unsigned short Tl[64][72];
  const int tid = threadIdx.x;
  const int b = blockIdx.z, c0 = blockIdx.y * 64, t0 = blockIdx.x * 64;
  const int cl = tid >> 2, j16 = (tid & 3) * 16;
  const int c = c0 + cl;
  const int grp = c >> 4;
  const float mean = stats[((size_t)b * 32 + grp) * 2];
  const float rstd = stats[((size_t)b * 32 + grp) * 2 + 1];
  const float ga = gamma[c] * rstd;
  const float be = beta[c] - mean * ga;
  const float* src = x + ((size_t)b * Cc + c) * Tt + t0 + j16;
#pragma unroll
  for (int q = 0; q < 4; ++q) {
    const float4 v = *(const float4*)(src + q * 4);
    Tl[j16 + q * 4 + 0][cl] = f2bf(v.x * ga + be);
    Tl[j16 + q * 4 + 1][cl] = f2bf(v.y * ga + be);
    Tl[j16 + q * 4 + 2][cl] = f2bf(v.z * ga + be);
    Tl[j16 + q * 4 + 3][cl] = f2bf(v.w * ga + be);
  }
  __syncthreads();
  const int tl = tid >> 2, i16 = (tid & 3) * 16;
  unsigned short* dst = hT + ((size_t)b * Tt + t0 + tl) * Cc + c0 + i16;
  *(u16x8*)dst = *(const u16x8*)&Tl[tl][i16];
  *(u16x8*)(dst + 8) = *(const u16x8*)&Tl[tl][i16 + 8];
}

// ---------------------------------------------------------------------------
// K3: fp32 -> bf16 convert (weights).
// ---------------------------------------------------------------------------
__global__ __launch_bounds__(256) void cvt_bf16(const float* __restrict__ in,
                                                unsigned short* __restrict__ out, int n4) {
  const int i = blockIdx.x * 256 + threadIdx.x;
  if (i < n4) {
    const float4 v = *(const float4*)(in + (size_t)i * 4);
    ushort4 o;
    o.x = f2bf(v.x); o.y = f2bf(v.y); o.z = f2bf(v.z); o.w = f2bf(v.w);
    *(ushort4*)(out + (size_t)i * 4) = o;
  }
}

// ---------------------------------------------------------------------------
// K4: bf16 transpose 64x64: qkv [b][3C][t] (Q,K) -> qkt [(bh*2+w)][t][64].
// Q (which==0) pre-scaled by 0.125*log2(e) -> scores land in log2 domain.
// ---------------------------------------------------------------------------
__global__ __launch_bounds__(256) void qk_trans(const unsigned short* __restrict__ qkv,
                                                unsigned short* __restrict__ qkt) {
  __shared__ unsigned short Tl[64][72];
  const int tid = threadIdx.x;
  const int t0 = blockIdx.x * 64;
  const int bhw = blockIdx.y;  // (b*8+h)*2 + which
  const int b = bhw >> 4, hw = bhw & 15;
  const int h = hw >> 1, which = hw & 1;
  const unsigned short* src =
      qkv + ((size_t)b * (3 * Cc) + h * 192 + which * 64) * Tt + t0;
  const int dl = tid >> 2, j16 = (tid & 3) * 16;
  u16x8 a0 = *(const u16x8*)(src + (size_t)dl * Tt + j16);
  u16x8 a1 = *(const u16x8*)(src + (size_t)dl * Tt + j16 + 8);
  if (which == 0) {
    const float qs = 0.125f * 1.44269504f;
#pragma unroll
    for (int q = 0; q < 8; ++q) {
      a0[q] = f2bf(bf2f(a0[q]) * qs);
      a1[q] = f2bf(bf2f(a1[q]) * qs);
    }
  }
#pragma unroll
  for (int q = 0; q < 8; ++q) Tl[j16 + q][dl] = a0[q];
#pragma unroll
  for (int q = 0; q < 8; ++q) Tl[j16 + 8 + q][dl] = a1[q];
  __syncthreads();
  const int tl = tid >> 2, i16 = (tid & 3) * 16;
  unsigned short* dst = qkt + ((size_t)bhw * Tt + t0 + tl) * 64 + i16;
  *(u16x8*)dst = *(const u16x8*)&Tl[tl][i16];
  *(u16x8*)(dst + 8) = *(const u16x8*)&Tl[tl][i16 + 8];
}

// ---------------------------------------------------------------------------
// K5: bf16 MFMA GEMM (m97 structure), BM=BN=128, BK=32, 4 waves.
// ---------------------------------------------------------------------------
template <int MODE>
__global__ __launch_bounds__(256) void gemm_mfma(const unsigned short* __restrict__ A,
                                                 const unsigned short* __restrict__ Bt,
                                                 const float* __restrict__ bias,
                                                 const float* __restrict__ res,
                                                 unsigned short* __restrict__ outb,
                                                 float* __restrict__ outf, int M) {
  __shared__ unsigned short Al[128 * 32];
  __shared__ unsigned short Bl[128 * 32];
  const int tid = threadIdx.x;
  const int n0 = blockIdx.x * 128, m0 = blockIdx.y * 128;
  const size_t z = blockIdx.z;
  const int l = tid & 63, il = l & 15, g = l >> 4;
  const int w = tid >> 6;
  const int wm = (w >> 1) * 64, wn = (w & 1) * 64;

  const unsigned short* Bz = Bt + z * (size_t)Tt * Cc;
  const unsigned short* Ap = A + (size_t)(m0 + (tid >> 2)) * Cc + (tid & 3) * 8;
  const unsigned short* Bp = Bz + (size_t)(n0 + (tid >> 2)) * Cc + (tid & 3) * 8;
  char* ldsA = (char*)Al + w * 1024;
  char* ldsB = (char*)Bl + w * 1024;

  f32x4 acc[4][4] = {};
  for (int k0 = 0; k0 < Cc; k0 += 32) {
    async16(Ap + k0, ldsA);
    async16(Ap + (size_t)64 * Cc + k0, ldsA + 4096);
    async16(Bp + k0, ldsB);
    async16(Bp + (size_t)64 * Cc + k0, ldsB + 4096);
    __syncthreads();
    short8 af[4], bf[4];
#pragma unroll
    for (int i = 0; i < 4; ++i)
      af[i] = *(const short8*)(Al + (wm + i * 16 + il) * 32 + g * 8);
#pragma unroll
    for (int j = 0; j < 4; ++j)
      bf[j] = *(const short8*)(Bl + (wn + j * 16 + il) * 32 + g * 8);
    __builtin_amdgcn_s_setprio(1);
#pragma unroll
    for (int i = 0; i < 4; ++i)
#pragma unroll
      for (int j = 0; j < 4; ++j)
        acc[i][j] = __builtin_amdgcn_mfma_f32_16x16x32_bf16(af[i], bf[j], acc[i][j], 0, 0, 0);
    __builtin_amdgcn_s_setprio(0);
    __syncthreads();
  }

#pragma unroll
  for (int i = 0; i < 4; ++i) {
#pragma unroll
    for (int r = 0; r < 4; ++r) {
      const int m = m0 + wm + i * 16 + 4 * g + r;
      const float bv = bias[m];
#pragma unroll
      for (int j = 0; j < 4; ++j) {
        const int n = n0 + wn + j * 16 + il;
        const float v = acc[i][j][r] + bv;
        const size_t idx = (z * (size_t)M + m) * Tt + n;
        if (MODE == 0) {
          outb[idx] = f2bf(v);
        } else {
          outf[idx] = v + res[idx];
        }
      }
    }
  }
}

// ---------------------------------------------------------------------------
// K6: MFMA flash attention v3.
// Block = 4 waves, QBLK=64 (wave w owns q rows w*16..w*16+15), KVBLK=64,
// K/V double-buffered via global_load_lds w/ XOR-swizzled source (32KB LDS ->
// 4 blocks/CU). Scores in log2 domain (Q pre-scaled by 0.125*log2e).
// P stays IN REGISTERS: cvt_pk_bf16 + permlane32_swap + permlane16_swap
// redistribute P from the S^T output layout to the PV A-fragment layout.
// Defer-max (THR=8): skip rescale when no lane's max exceeds m_run+8.
// Grid 1024 flat, XCD-swizzled.
// ---------------------------------------------------------------------------
__global__ __launch_bounds__(256, 4) void attn_mfma3(const unsigned short* __restrict__ qkt,
                                                     const unsigned short* __restrict__ qkvc,
                                                     unsigned short* __restrict__ attnoT) {
  __shared__ unsigned short KVs[2][2][64 * 64];  // [buf][K/V][row*64+col] swizzled

  const int tid = threadIdx.x;
  const int w = tid >> 6, l = tid & 63, il = l & 15, g = l >> 4;

  // XCD-aware swizzle (1024 % 8 == 0 -> bijective)
  const int bid = blockIdx.x;
  const int swz = (bid & 7) * 128 + (bid >> 3);
  const int bh = swz >> 5, qt = swz & 31;
  const int b = bh >> 3, h = bh & 7;
  const int q0 = qt * 64;

  const unsigned short* Qb = qkt + (size_t)(bh * 2) * Tt * 64;
  const char* Kb = (const char*)(Qb + (size_t)Tt * 64);
  const char* Vb = (const char*)(qkvc + ((size_t)b * (3 * Cc) + h * 192 + 128) * Tt);

  // Q fragment (B-operand): col q = q0 + w*16 + il, k contiguous
  short8 qf[2];
  {
    const unsigned short* qp = Qb + (size_t)(q0 + w * 16 + il) * 64 + g * 8;
    qf[0] = *(const short8*)qp;
    qf[1] = *(const short8*)(qp + 32);
  }

  float m_run = -1e30f, l_run = 0.f;
  f32x4 acco[4] = {};  // O[q=4g+r][d=j*16+il]

  const int srow = w * 16 + (l >> 3);
  const int scol = ((l & 7) ^ (l >> 3)) << 4;

  auto stage = [&](int buf, int s0) {
    char* kd = (char*)&KVs[buf][0][0] + w * 2048;
    char* vd = (char*)&KVs[buf][1][0] + w * 2048;
    async16(Kb + (size_t)(s0 + srow) * 128 + scol, kd);
    async16(Kb + (size_t)(s0 + srow + 8) * 128 + scol, kd + 1024);
    async16(Vb + (size_t)srow * (Tt * 2) + (size_t)s0 * 2 + scol, vd);
    async16(Vb + (size_t)(srow + 8) * (Tt * 2) + (size_t)s0 * 2 + scol, vd + 1024);
  };

  stage(0, 0);
  __syncthreads();
  int cur = 0;

  const int NT = Tt / 64;
  for (int t = 0; t < NT; ++t) {
    if (t + 1 < NT) stage(cur ^ 1, (t + 1) * 64);
    const unsigned short* Kc = &KVs[cur][0][0];
    const unsigned short* Vc = &KVs[cur][1][0];

    // S^T = K·Q^T : lane (il,g) gets S[s=16i+4g+r][q = w-strip + il], log2 units
    f32x4 accs[4] = {};
    __builtin_amdgcn_s_setprio(1);
#pragma unroll
    for (int ks = 0; ks < 2; ++ks) {
#pragma unroll
      for (int i = 0; i < 4; ++i) {
        const short8 kf =
            *(const short8*)(Kc + (i * 16 + il) * 64 + ((((ks << 2) + g) ^ (il & 7)) << 3));
        accs[i] = __builtin_amdgcn_mfma_f32_16x16x32_bf16(kf, qf[ks], accs[i], 0, 0, 0);
      }
    }
    __builtin_amdgcn_s_setprio(0);

    // per-lane max of 16 values
    float pmax = accs[0][0];
#pragma unroll
    for (int i = 0; i < 4; ++i)
#pragma unroll
      for (int r = 0; r < 4; ++r) pmax = fmaxf(pmax, accs[i][r]);

    const bool noskip = !__all(pmax <= m_run + 8.0f);
    float alpha = 1.f;
    if (noskip) {
      float mx = pmax;
      mx = fmaxf(mx, __shfl_xor(mx, 16));
      mx = fmaxf(mx, __shfl_xor(mx, 32));
      const float mnew = fmaxf(m_run, mx);
      alpha = __builtin_amdgcn_exp2f(m_run - mnew);
      m_run = mnew;
    }

    // p = exp2(s - m); pack to bf16 pairs pk[i][h] = (r=2h, r=2h+1)
    float rsum = 0.f;
    uint32_t pk[4][2];
#pragma unroll
    for (int i = 0; i < 4; ++i) {
      const float p0 = __builtin_amdgcn_exp2f(accs[i][0] - m_run);
      const float p1 = __builtin_amdgcn_exp2f(accs[i][1] - m_run);
      const float p2 = __builtin_amdgcn_exp2f(accs[i][2] - m_run);
      const float p3 = __builtin_amdgcn_exp2f(accs[i][3] - m_run);
      rsum += p0 + p1 + p2 + p3;
      asm("v_cvt_pk_bf16_f32 %0, %1, %2" : "=v"(pk[i][0]) : "v"(p0), "v"(p1));
      asm("v_cvt_pk_bf16_f32 %0, %1, %2" : "=v"(pk[i][1]) : "v"(p2), "v"(p3));
    }
    rsum += __shfl_xor(rsum, 16);
    rsum += __shfl_xor(rsum, 32);

    if (noskip) {
      l_run = l_run * alpha + rsum;
      float ar[4];
#pragma unroll
      for (int r = 0; r < 4; ++r) ar[r] = __shfl(alpha, 4 * g + r);
#pragma unroll
      for (int j = 0; j < 4; ++j) {
        f32x4 tv = acco[j];
        tv[0] *= ar[0]; tv[1] *= ar[1]; tv[2] *= ar[2]; tv[3] *= ar[3];
        acco[j] = tv;
      }
    } else {
      l_run += rsum;
    }

    // In-register P redistribution: target lane (il,g), frag[ks] dword j2 =
    // pk[2ks+(g>>1)][j2&1] from lane (il, (2g+(j2>>1))&3).
    // swap32 then swap16 on (A,B)=(pk[2ks][h], pk[2ks+1][h]) yields
    // (Rlo, Rhi) = dwords (j2 = 0+h, 2+h).
    uint32_t fr[2][4];
#pragma unroll
    for (int ks = 0; ks < 2; ++ks) {
#pragma unroll
      for (int hh = 0; hh < 2; ++hh) {
        uint32_t a = pk[2 * ks][hh], bq = pk[2 * ks + 1][hh];
        asm("v_permlane32_swap_b32 %0, %1" : "+v"(a), "+v"(bq));
        asm("v_permlane16_swap_b32 %0, %1" : "+v"(a), "+v"(bq));
        fr[ks][hh] = a;       // j2 = 0 + hh
        fr[ks][2 + hh] = bq;  // j2 = 2 + hh
      }
    }

    // O += P·V
    __builtin_amdgcn_s_setprio(1);
#pragma unroll
    for (int ks = 0; ks < 2; ++ks) {
      union { uint32_t u[4]; short8 v; } fu;
      fu.u[0] = fr[ks][0]; fu.u[1] = fr[ks][1];
      fu.u[2] = fr[ks][2]; fu.u[3] = fr[ks][3];
#pragma unroll
      for (int j = 0; j < 4; ++j) {
        const short8 vf =
            *(const short8*)(Vc + (j * 16 + il) * 64 + ((((ks << 2) + g) ^ (il & 7)) << 3));
        acco[j] = __builtin_amdgcn_mfma_f32_16x16x32_bf16(fu.v, vf, acco[j], 0, 0, 0);
      }
    }
    __builtin_amdgcn_s_setprio(0);

    __syncthreads();
    cur ^= 1;
  }

  // Epilogue
#pragma unroll
  for (int r = 0; r < 4; ++r) {
    const float li = 1.f / __shfl(l_run, 4 * g + r);
    const int tq = q0 + w * 16 + 4 * g + r;
    unsigned short* d0 = attnoT + ((size_t)b * Tt + tq) * Cc + h * 64 + il;
#pragma unroll
    for (int j = 0; j < 4; ++j) d0[j * 16] = f2bf(acco[j][r] * li);
  }
}

// ---------------------------------------------------------------------------
extern "C" void kernel_launch(void* const* d_in, const int* in_sizes, int n_in,
                              void* d_out, int out_size, void* d_ws, size_t ws_size,
                              hipStream_t stream) {
  const float* x = (const float*)d_in[0];
  const float* gamma = (const float*)d_in[1];
  const float* beta = (const float*)d_in[2];
  const float* w_qkv = (const float*)d_in[3];
  const float* b_qkv = (const float*)d_in[4];
  const float* w_proj = (const float*)d_in[5];
  const float* b_proj = (const float*)d_in[6];
  float* out = (float*)d_out;

  char* p = (char*)d_ws;
  float* stats = (float*)p;                  p += 256 * sizeof(float);
  unsigned short* hT = (unsigned short*)p;   p += (size_t)Bb * Tt * Cc * 2;
  unsigned short* wq = (unsigned short*)p;   p += (size_t)3 * Cc * Cc * 2;
  unsigned short* wp = (unsigned short*)p;   p += (size_t)Cc * Cc * 2;
  unsigned short* qkvc = (unsigned short*)p; p += (size_t)Bb * 3 * Cc * Tt * 2;
  unsigned short* qkt = (unsigned short*)p;  p += (size_t)Bb * Hh * 2 * Tt * 64 * 2;
  unsigned short* attnoT = (unsigned short*)p;

  gn_stats<<<dim3(Bb * 32), 256, 0, stream>>>(x, stats);
  norm_trans<<<dim3(Tt / 64, Cc / 64, Bb), 256, 0, stream>>>(x, stats, gamma, beta, hT);
  cvt_bf16<<<dim3((3 * Cc * Cc / 4 + 255) / 256), 256, 0, stream>>>(w_qkv, wq, 3 * Cc * Cc / 4);
  cvt_bf16<<<dim3((Cc * Cc / 4 + 255) / 256), 256, 0, stream>>>(w_proj, wp, Cc * Cc / 4);
  gemm_mfma<0><<<dim3(Tt / 128, (3 * Cc) / 128, Bb), 256, 0, stream>>>(
      wq, hT, b_qkv, nullptr, qkvc, nullptr, 3 * Cc);
  qk_trans<<<dim3(Tt / 64, Bb * Hh * 2), 256, 0, stream>>>(qkvc, qkt);
  attn_mfma3<<<dim3(1024), 256, 0, stream>>>(qkt, qkvc, attnoT);
  gemm_mfma<1><<<dim3(Tt / 128, Cc / 128, Bb), 256, 0, stream>>>(
      wp, attnoT, b_proj, x, nullptr, out, Cc);
}